// Round 5
// baseline (246.029 us; speedup 1.0000x reference)
//
#include <hip/hip_runtime.h>

// ROI bilinear pooling (tf.image.resize half-pixel centers), POOL=7.
// img: (1, 64, 64, 1024) fp32, NHWC. rois: (1, R, 4) int32 = [x, y, w, h].
// out: (1, R, 7, 7, 1024) fp32.
//
// R9 = ISOLATION PROBE (pre-committed after R8's decisive null).
// History: reads cut 25x (R8), occupancy 4->16 waves (R6), NT/plain,
// orderings (R5/R7) -- ALL invariant at ~236us total; the pool dispatch
// has never appeared in the top-5 counters (always <121us, hidden under
// the harness fills). This round deliberately halves the grid (256
// blocks, 2 serial jobs each -> 2x per-CU work) so the pool dispatch
// becomes the SLOWEST dispatch and surfaces its own counters.
// Decision table (pre-committed):
//   pool ~2x (190-240us) -> kernel-internal limiter; read VALUBusy next.
//   pool ~1x (110-140us) -> external (fill-writeback debt); ROOFLINE.
//   FETCH_SIZE ~200MB    -> store RMW pathology; fix coverage.
//   WRITE_SIZE >>205MB   -> write amplification; fix.

#define POOLSZ 7
#define IMG_H 64
#define IMG_W 64
#define IMG_C 1024
#define NUM_XCD 8
#define SPLITS 8                  // channel splits: 128 ch per job
#define CH_V4 (IMG_C / 4)         // 256 v4f per pixel
#define SPLIT_V4 (CH_V4 / SPLITS) // 32 v4f per split

typedef float v4f __attribute__((ext_vector_type(4)));

__device__ __forceinline__ int src_y0(int ry, int rh, int py) {
    const float scy  = (float)rh * (1.0f / (float)POOLSZ);
    const float srcy = ((float)py + 0.5f) * scy - 0.5f;
    const int   iy   = (int)floorf(srcy);
    return ry + min(max(iy, 0), rh - 1);
}

// Counting-sort the R*7 (roi,py) rows by source row y0 (64 bins).
__global__ __launch_bounds__(256) void row_sort_kernel(
    const int* __restrict__ rois, int* __restrict__ order,
    int* __restrict__ binStart, int R) {
    __shared__ int cnt[64];
    __shared__ int ofs[64];
    const int t = threadIdx.x;
    const int n = R * POOLSZ;
    if (t < 64) cnt[t] = 0;
    __syncthreads();
    for (int i = t; i < n; i += 256) {
        const int r  = i / POOLSZ;
        const int py = i - r * POOLSZ;
        const int y0 = src_y0(rois[r * 4 + 1], rois[r * 4 + 3], py) & 63;
        atomicAdd(&cnt[y0], 1);
    }
    __syncthreads();
    if (t == 0) {
        int s = 0;
        for (int i = 0; i < 64; ++i) { ofs[i] = s; binStart[i] = s; s += cnt[i]; }
        binStart[64] = s;
    }
    __syncthreads();
    for (int i = t; i < n; i += 256) {
        const int r  = i / POOLSZ;
        const int py = i - r * POOLSZ;
        const int y0 = src_y0(rois[r * 4 + 1], rois[r * 4 + 3], py) & 63;
        const int p  = atomicAdd(&ofs[y0], 1);
        order[p] = i;
    }
}

// PROBE: 256 blocks; each processes 2 (bin,split) jobs serially.
// Per job: stage rows {bin, bin+1} x 128 ch in LDS (64 KB), then each
// 32-lane group streams the bin's (roi,py) rows from LDS.
__global__ __launch_bounds__(256, 1) void roi_pool_bin_probe(
    const float* __restrict__ img,
    const int* __restrict__ rois,
    float* __restrict__ out,
    const int* __restrict__ order,
    const int* __restrict__ binStart) {
    __shared__ v4f lds[2 * IMG_W * SPLIT_V4];    // 64 KB, reused across jobs
    const int t = threadIdx.x;
    v4f* __restrict__ out4 = (v4f*)out;

    for (int job = blockIdx.x; job < 64 * SPLITS; job += gridDim.x) {
        const int bin   = job >> 3;              // 0..63 = source row y0
        const int split = job & (SPLITS - 1);    // 0..7  = 128-ch slice
        const int start = binStart[bin];
        const int cnt   = binStart[bin + 1] - start;

        __syncthreads();   // WAR: previous job's LDS readers are done
        {   // stage: 4096 v4f, 16 per thread, coalesced 512 B runs
            const v4f* __restrict__ img4 = (const v4f*)img;
            const int y_hi = min(bin + 1, IMG_H - 1);
#pragma unroll
            for (int k = 0; k < 16; ++k) {
                const int j   = t + k * 256;     // 0..4095
                const int row = j >> 11;         // 0 | 1
                const int rem = j & 2047;
                const int x   = rem >> 5;        // 0..63
                const int c4  = rem & 31;        // 0..31
                const int y   = row ? y_hi : bin;
                lds[j] = img4[((size_t)(y * IMG_W + x)) * CH_V4
                              + split * SPLIT_V4 + c4];
            }
        }
        __syncthreads();

        const int grp  = t >> 5;   // 0..7: concurrent row streams
        const int lane = t & 31;   // v4f channel within split

        for (int row = grp; row < cnt; row += 8) {
            const int rid = order[start + row];  // = r*7 + py
            const int r   = rid / POOLSZ;
            const int py  = rid - r * POOLSZ;
            const int4 roi = ((const int4*)rois)[r];
            const int rx = roi.x, ry = roi.y, rw = roi.z, rh = roi.w;

            const float scy  = (float)rh * (1.0f / (float)POOLSZ);
            const float srcy = ((float)py + 0.5f) * scy - 0.5f;
            const float fy   = floorf(srcy);
            const float ty   = srcy - fy;
            const int   iy   = (int)fy;
            // y0 == bin by construction; y1 in {bin, bin+1}
            const int y1 = ry + min(max(iy + 1, 0), rh - 1);
            const int l1 = (y1 - bin) << 11;     // 0 or 2048 (v4f units)

            const float scx = (float)rw * (1.0f / (float)POOLSZ);
            const size_t obase =
                (size_t)rid * (POOLSZ * CH_V4) + split * SPLIT_V4 + lane;
#pragma unroll
            for (int px = 0; px < POOLSZ; ++px) {
                const float srcx = ((float)px + 0.5f) * scx - 0.5f;
                const float fx   = floorf(srcx);
                const float tx   = srcx - fx;
                const int   ix   = (int)fx;
                const int xo0 = (rx + min(max(ix,     0), rw - 1)) << 5;
                const int xo1 = (rx + min(max(ix + 1, 0), rw - 1)) << 5;

                const v4f a = lds[xo0 + lane];
                const v4f b = lds[xo1 + lane];
                const v4f c = lds[l1 + xo0 + lane];
                const v4f d = lds[l1 + xo1 + lane];

                const v4f top = a + (b - a) * tx;
                const v4f bot = c + (d - c) * tx;
                out4[obase + (size_t)px * CH_V4] = top + (bot - top) * ty;
            }
        }
    }
}

// Fallback (no workspace): R6 streaming row kernel, identity order.
__global__ __launch_bounds__(256, 4) void roi_pool_row_kernel(
    const float* __restrict__ img,
    const int* __restrict__ rois,
    float* __restrict__ out) {
    const int rowIdx = blockIdx.x;
    const int r  = rowIdx / POOLSZ;
    const int py = rowIdx - r * POOLSZ;

    const int4 roi = ((const int4*)rois)[r];
    const int rx = roi.x, ry = roi.y, rw = roi.z, rh = roi.w;

    const float scy  = (float)rh * (1.0f / (float)POOLSZ);
    const float srcy = ((float)py + 0.5f) * scy - 0.5f;
    const float fy   = floorf(srcy);
    const float ty   = srcy - fy;
    const int   iy   = (int)fy;
    const int   y0   = ry + min(max(iy,     0), rh - 1);
    const int   y1   = ry + min(max(iy + 1, 0), rh - 1);

    const int c4 = threadIdx.x;
    const v4f* __restrict__ base = (const v4f*)img + c4;
    const int rb0 = y0 * (IMG_W * CH_V4);
    const int rb1 = y1 * (IMG_W * CH_V4);
    v4f* __restrict__ dst =
        (v4f*)out + ((size_t)r * POOLSZ + py) * POOLSZ * CH_V4 + c4;

    const float scx = (float)rw * (1.0f / (float)POOLSZ);
#pragma unroll
    for (int px = 0; px < POOLSZ; ++px) {
        const float srcx = ((float)px + 0.5f) * scx - 0.5f;
        const float fx   = floorf(srcx);
        const float tx   = srcx - fx;
        const int   ix   = (int)fx;
        const int   xo0  = (rx + min(max(ix,     0), rw - 1)) * CH_V4;
        const int   xo1  = (rx + min(max(ix + 1, 0), rw - 1)) * CH_V4;

        const v4f a = base[rb0 + xo0];
        const v4f b = base[rb0 + xo1];
        const v4f c = base[rb1 + xo0];
        const v4f d = base[rb1 + xo1];

        const v4f top = a + (b - a) * tx;
        const v4f bot = c + (d - c) * tx;
        dst[px * CH_V4] = top + (bot - top) * ty;
    }
}

extern "C" void kernel_launch(void* const* d_in, const int* in_sizes, int n_in,
                              void* d_out, int out_size, void* d_ws, size_t ws_size,
                              hipStream_t stream) {
    const float* img  = (const float*)d_in[0];
    const int*   rois = (const int*)d_in[1];
    float*       out  = (float*)d_out;
    const int R = in_sizes[1] / 4;                  // rois: (1, R, 4)
    const int n_rows = R * POOLSZ;

    const size_t ws_need = (size_t)(n_rows + 65) * sizeof(int);
    if (ws_size >= ws_need) {
        int* order    = (int*)d_ws;
        int* binStart = order + n_rows;
        row_sort_kernel<<<1, 256, 0, stream>>>(rois, order, binStart, R);
        roi_pool_bin_probe<<<256, 256, 0, stream>>>(
            img, rois, out, order, binStart);
    } else {
        roi_pool_row_kernel<<<n_rows, 256, 0, stream>>>(img, rois, out);
    }
}

// Round 6
// 233.600 us; speedup vs baseline: 1.0532x; 1.0532x over previous
//
#include <hip/hip_runtime.h>

// ROI bilinear pooling (tf.image.resize half-pixel centers), POOL=7.
// img: (1, 64, 64, 1024) fp32, NHWC. rois: (1, R, 4) int32 = [x, y, w, h].
// out: (1, R, 7, 7, 1024) fp32.
//
// R10 = revert R9 probe; resubmit best-measured variant (R5, 232.6us).
// R9 probe conclusion: pool kernel is ~10-20us (2x per-CU work moved
// total by only +10us and pool never surfaced in top-5 counters). The
// 232-246us floor across six structurally different kernels is harness
// poison-fill traffic (~2 x 822 MB @ ~6.7 TB/s ~= 244us), external to
// the kernel. Pool is at its own write-BW floor; no kernel-side lever
// above the noise band remains.

#define POOLSZ 7
#define IMG_H 64
#define IMG_W 64
#define IMG_C 1024
#define NUM_XCD 8

typedef float v4f __attribute__((ext_vector_type(4)));

// Counting-sort ROI indices by y into order[] (workspace). One block, ~3 us.
__global__ __launch_bounds__(256) void roi_sort_kernel(
    const int* __restrict__ rois, int* __restrict__ order, int R) {
    __shared__ int cnt[64];
    __shared__ int ofs[64];
    const int t = threadIdx.x;
    if (t < 64) cnt[t] = 0;
    __syncthreads();
    for (int r = t; r < R; r += 256) {
        const int y = rois[r * 4 + 1] & 63;
        atomicAdd(&cnt[y], 1);
    }
    __syncthreads();
    if (t == 0) {
        int s = 0;
        for (int i = 0; i < 64; ++i) { ofs[i] = s; s += cnt[i]; }
    }
    __syncthreads();
    for (int r = t; r < R; r += 256) {
        const int y = rois[r * 4 + 1] & 63;
        const int p = atomicAdd(&ofs[y], 1);
        order[p] = r;   // permutation of 0..R-1 by construction
    }
}

// One block per (roi, py) row: 7 output cells. 256 threads, each owns a
// float4 channel slice, issues all 28 bilinear taps up-front, blends,
// stores 7 outputs (each wave store = 1 KB contiguous).
__global__ __launch_bounds__(256, 1) void roi_pool_row_kernel(
    const float* __restrict__ img,
    const int* __restrict__ rois,
    float* __restrict__ out,
    int roisPerXcd,              // R/8 when R%8==0, else 0 (identity mapping)
    const int* __restrict__ order) {  // y-sorted ROI permutation, or null
    int rIdx, py;
    if (roisPerXcd > 0) {
        const int xcd   = blockIdx.x & (NUM_XCD - 1);
        const int local = blockIdx.x >> 3;           // 0 .. R/8*7-1
        rIdx = xcd * roisPerXcd + local / POOLSZ;
        py   = local % POOLSZ;
    } else {
        rIdx = blockIdx.x / POOLSZ;
        py   = blockIdx.x % POOLSZ;
    }
    const int r = order ? order[rIdx] : rIdx;   // spatial (y-band) ordering

    const int4 roi = ((const int4*)rois)[r];
    const int rx = roi.x, ry = roi.y, rw = roi.z, rh = roi.w;

    // y coords: src = (py+0.5)*h/7 - 0.5; lerp from unclipped floor (ref semantics)
    const float scy  = (float)rh * (1.0f / (float)POOLSZ);
    const float srcy = ((float)py + 0.5f) * scy - 0.5f;
    const float fy   = floorf(srcy);
    const float ty   = srcy - fy;
    const int   iy   = (int)fy;
    const int   y0   = ry + min(max(iy,     0), rh - 1);
    const int   y1   = ry + min(max(iy + 1, 0), rh - 1);

    // x coords for all 7 cells
    int   x0[POOLSZ], x1[POOLSZ];
    float tx[POOLSZ];
    const float scx = (float)rw * (1.0f / (float)POOLSZ);
#pragma unroll
    for (int px = 0; px < POOLSZ; ++px) {
        const float srcx = ((float)px + 0.5f) * scx - 0.5f;
        const float fx   = floorf(srcx);
        tx[px] = srcx - fx;
        const int ix = (int)fx;
        x0[px] = rx + min(max(ix,     0), rw - 1);
        x1[px] = rx + min(max(ix + 1, 0), rw - 1);
    }

    const int c4 = threadIdx.x;  // 0..255: float4 channel slice
    const v4f* row0 = (const v4f*)(img + (size_t)y0 * IMG_W * IMG_C) + c4;
    const v4f* row1 = (const v4f*)(img + (size_t)y1 * IMG_W * IMG_C) + c4;

    // Issue all 28 loads before any arithmetic (deep MLP).
    v4f a[POOLSZ], b[POOLSZ], c[POOLSZ], d[POOLSZ];
#pragma unroll
    for (int px = 0; px < POOLSZ; ++px) {
        a[px] = row0[(size_t)x0[px] * (IMG_C / 4)];
        b[px] = row0[(size_t)x1[px] * (IMG_C / 4)];
        c[px] = row1[(size_t)x0[px] * (IMG_C / 4)];
        d[px] = row1[(size_t)x1[px] * (IMG_C / 4)];
    }

    // out = (a*(1-tx)+b*tx)*(1-ty) + (c*(1-tx)+d*tx)*ty
    v4f* dst = (v4f*)out + ((size_t)r * POOLSZ + py) * POOLSZ * (IMG_C / 4) + c4;
#pragma unroll
    for (int px = 0; px < POOLSZ; ++px) {
        const v4f top = a[px] + (b[px] - a[px]) * tx[px];
        const v4f bot = c[px] + (d[px] - c[px]) * tx[px];
        const v4f o   = top + (bot - top) * ty;
        dst[(size_t)px * (IMG_C / 4)] = o;   // plain store
    }
}

extern "C" void kernel_launch(void* const* d_in, const int* in_sizes, int n_in,
                              void* d_out, int out_size, void* d_ws, size_t ws_size,
                              hipStream_t stream) {
    const float* img  = (const float*)d_in[0];
    const int*   rois = (const int*)d_in[1];
    float*       out  = (float*)d_out;
    const int R = in_sizes[1] / 4;                  // rois: (1, R, 4)
    const int n_rows = R * POOLSZ;                  // 1024*7 = 7168 blocks
    const int roisPerXcd = (R % NUM_XCD == 0) ? (R / NUM_XCD) : 0;

    int* order = nullptr;
    if (ws_size >= (size_t)R * sizeof(int)) {
        order = (int*)d_ws;
        roi_sort_kernel<<<1, 256, 0, stream>>>(rois, order, R);
    }
    roi_pool_row_kernel<<<n_rows, 256, 0, stream>>>(img, rois, out, roisPerXcd, order);
}